// Round 7
// baseline (385.956 us; speedup 1.0000x reference)
//
#include <hip/hip_runtime.h>
#include <hip/hip_bf16.h>

// Problem constants
#define NB 256
#define NACT 21
#define NA 8192
#define NE 262144
#define CSR_CAP 128
#define NBLK 256
#define NTHR 1024

typedef __attribute__((ext_vector_type(8))) short short8;
typedef __attribute__((ext_vector_type(4))) float float4v;

__device__ inline float wsum64(float v) {
#pragma unroll
  for (int m = 32; m > 0; m >>= 1) v += __shfl_xor(v, m, 64);
  return v;
}

__device__ inline unsigned short f2bf(float f) {
  union { __hip_bfloat16 h; unsigned short u; } cv;
  cv.h = __float2bfloat16(f);
  return cv.u;
}

// Grid barrier: release-add, RELAXED poll, final acquire. Bounded spin ->
// wrong results (caught by absmax) instead of hang on failure.
__device__ inline void gridbar(int* bar, int idx) {
  __syncthreads();
  if (threadIdx.x == 0) {
    __hip_atomic_fetch_add(&bar[idx], 1, __ATOMIC_RELEASE, __HIP_MEMORY_SCOPE_AGENT);
    int guard = 0;
    while (__hip_atomic_load(&bar[idx], __ATOMIC_RELAXED, __HIP_MEMORY_SCOPE_AGENT) < NBLK &&
           guard < (1 << 22)) {
      guard++;
      __builtin_amdgcn_s_sleep(8);
    }
    (void)__hip_atomic_load(&bar[idx], __ATOMIC_ACQUIRE, __HIP_MEMORY_SCOPE_AGENT);
  }
  __syncthreads();
}

// ---------------- dispatch 1: zero cnt/bar + action passthrough ----------------
__global__ void k_init(const int* action, int* cnt, int* bar, float* out) {
  int i = blockIdx.x * 256 + threadIdx.x;  // 33*256 = 8448 threads
  if (i < NA) cnt[i] = 0;
  if (i < 16) bar[i] = 0;
  if (i < NB) out[i] = (float)action[i];
}

// ---------------- dispatch 2: everything, 256 blocks x 1024 threads ----------------
__global__ __launch_bounds__(NTHR, 4) void k_mega(
    const float* __restrict__ x, const float* __restrict__ x_msg,
    const int* __restrict__ edges,
    const float* __restrict__ c1w, const float* __restrict__ c1b,
    const float* __restrict__ c2w, const float* __restrict__ c2b,
    const float* __restrict__ fcw, const float* __restrict__ fcb,
    const float* __restrict__ muw, const float* __restrict__ mub,
    const float* __restrict__ msgw, const float* __restrict__ msgb,
    const float* __restrict__ g1w, const float* __restrict__ g1b,
    const float* __restrict__ g2w, const float* __restrict__ g2b,
    const int* __restrict__ action,
    float* h1024, float* hidden, float* es2, float* dinv, float* xs2,
    float* gbuf2, float* wpart, unsigned short* w2t, int* cnt,
    unsigned short* csr, int* bar, float* out) {
  union SM {
    struct { float red[32][17]; float b2s[32]; } w2;
    struct { float xs[845]; float w1s[1440]; float c1s[1152]; float w2s[64 * 73]; } cv;
    struct { float As[16][132]; float Bs[32][132]; } fc;
    struct { float muT[10752]; float hrows[2048]; } hd;
    struct { unsigned short vbf[512]; float vf[512]; float pl[8192]; float sl[1024];
             float wp[16][17]; float wsf[17]; } mg;
  };
  __shared__ __align__(16) union SM sm;
  int t = threadIdx.x, blk = blockIdx.x;
  int wave = t >> 6, lane = t & 63;
  int gid = blk * NTHR + t;  // 0..262143

  //================ P0: CSR build + W2 prep + conv ================
  {  // CSR: exactly 1 edge per thread (NE == NBLK*NTHR)
    int s = edges[2 * gid], d = edges[2 * gid + 1];
    int slot = atomicAdd(&cnt[d], 1);
    if (slot < CSR_CAP) csr[d * CSR_CAP + slot] = (unsigned short)s;
  }
  {  // W2 transpose->bf16 + per-block column/bias partials (no atomics)
    if (t < 512) {
      int jj = t >> 4, k = t & 15;
      int j = blk * 32 + jj;
      float w = g2w[k * 8192 + j];
      w2t[j * 16 + k] = f2bf(w);
      sm.w2.red[jj][k] = w;
    }
    if (t < 32) sm.w2.b2s[t] = g2b[blk * 32 + t];
    __syncthreads();
    if (t < 16) {
      float s = 0.0f;
#pragma unroll
      for (int q = 0; q < 32; q++) s += sm.w2.red[q][t];
      wpart[blk * 17 + t] = s;
    } else if (t == 16) {
      float s = 0.0f;
#pragma unroll
      for (int q = 0; q < 32; q++) s += sm.w2.b2s[q];
      wpart[blk * 17 + 16] = s;
    }
    __syncthreads();
  }
  {  // fused conv1+conv2, one block per image
    for (int i = t; i < 845; i += NTHR) sm.cv.xs[i] = x[blk * 845 + i];
    for (int i = t; i < 1440; i += NTHR) sm.cv.w1s[i] = c1w[i];
    __syncthreads();
    for (int idx = t; idx < 1152; idx += NTHR) {
      int oc = idx / 36, p = idx - oc * 36;
      int oy = p / 6, ox = p - oy * 6;
      float acc = c1b[oc];
      const float* wp = &sm.cv.w1s[oc * 45];
#pragma unroll
      for (int ic = 0; ic < 5; ic++)
#pragma unroll
        for (int ky = 0; ky < 3; ky++)
#pragma unroll
          for (int kx = 0; kx < 3; kx++)
            acc += sm.cv.xs[ic * 169 + (oy * 2 + ky) * 13 + ox * 2 + kx] * wp[ic * 9 + ky * 3 + kx];
      sm.cv.c1s[idx] = fmaxf(acc, 0.0f);
    }
    int p = t & 15, oc = t >> 4;  // 64 ocs x 16 pixels = 1024, one output each
    int oy = p >> 2, ox = p & 3;
    float a0 = c2b[oc];
    for (int icb = 0; icb < 32; icb += 8) {
      __syncthreads();
      for (int i = t; i < 4608; i += NTHR) {
        int o = i / 72, r = i - o * 72;
        sm.cv.w2s[o * 73 + r] = c2w[o * 288 + icb * 9 + r];
      }
      __syncthreads();
#pragma unroll
      for (int ic = 0; ic < 8; ic++)
#pragma unroll
        for (int ky = 0; ky < 3; ky++)
#pragma unroll
          for (int kx = 0; kx < 3; kx++)
            a0 += sm.cv.c1s[(icb + ic) * 36 + (oy + ky) * 6 + ox + kx] *
                  sm.cv.w2s[oc * 73 + ic * 9 + ky * 3 + kx];
    }
    h1024[blk * 1024 + oc * 16 + p] = fmaxf(a0, 0.0f);
  }
  gridbar(bar, 0);

  //================ P1: dinv/xs2 + FC (16x32 tile, lane-pair K-split) ================
  if (gid < NA) {
    float d = rsqrtf((float)cnt[gid] + 1.0f);
    dinv[gid] = d;
    xs2[gid] = d * x_msg[gid];
  }
  {
    int rb = (blk >> 4) * 16, cb = (blk & 15) * 32;
    int r = t >> 6;                       // wave id = row 0..15
    int c = (t & 63) >> 1, half = t & 1;  // 32 cols, lane-pair K split
    float acc = 0.0f;
    for (int kb = 0; kb < 1024; kb += 128) {
      __syncthreads();
      if (t < 512) {
        int idx = t * 4, ar = idx >> 7, ak = idx & 127;
        *(float4*)&sm.fc.As[ar][ak] = *(const float4*)&h1024[(rb + ar) * 1024 + kb + ak];
      }
      {
        int idb = t * 4, br = idb >> 7, bk = idb & 127;
        *(float4*)&sm.fc.Bs[br][bk] = *(const float4*)&fcw[(cb + br) * 1024 + kb + bk];
      }
      __syncthreads();
      int k0 = half * 64;
#pragma unroll 16
      for (int kk = 0; kk < 64; kk += 4) {
        float4 a = *(const float4*)&sm.fc.As[r][k0 + kk];
        float4 b = *(const float4*)&sm.fc.Bs[c][k0 + kk];
        acc += a.x * b.x + a.y * b.y + a.z * b.z + a.w * b.w;
      }
    }
    acc += __shfl_xor(acc, 1, 64);
    if (half == 0) hidden[(rb + r) * 512 + cb + c] = fmaxf(acc + fcb[cb + c], 0.0f);
  }
  gridbar(bar, 1);

  //================ P2: head (blocks 0..63) | enc (blocks 64..255) ================
  if (blk < 64) {
    int b0 = blk * 4;
    for (int i = t; i < 10752; i += NTHR) {
      int a = i >> 9, k = i & 511;
      sm.hd.muT[k * 21 + a] = muw[i];
    }
    for (int i = t; i < 2048; i += NTHR) sm.hd.hrows[i] = hidden[b0 * 512 + i];
    __syncthreads();
    if (wave < 4) {
      int b = b0 + wave;
      float logit = -1e30f;
      if (lane < NACT) {
        float acc = mub[lane];
        const float* hr = &sm.hd.hrows[wave * 512];
        for (int k = 0; k < 512; k++) acc += hr[k] * sm.hd.muT[k * 21 + lane];
        logit = acc;
      }
      float m = logit;
#pragma unroll
      for (int s = 32; s > 0; s >>= 1) m = fmaxf(m, __shfl_xor(m, s, 64));
      float e = (lane < NACT) ? __expf(logit - m) : 0.0f;
      float se = wsum64(e);
      float swl = wsum64(e * logit);
      float lse = m + __logf(se);
      int act = action[b];
      if (lane == 0) out[8704 + b] = lse - swl / se;   // entropy
      if (lane == act) out[8448 + b] = logit - lse;    // log_prob
    }
  } else {  // enc: es2[j] = dinv[j] * (hidden[0].msg_w[j] + msgb[j])
    int wg = (blk - 64) * 16 + wave;  // 0..3071
    for (int j = wg; j < NA; j += 3072) {
      const float* wp = &msgw[j * 512 + lane * 8];
      float4 w0 = *(const float4*)(wp);
      float4 w1 = *(const float4*)(wp + 4);
      float4 h0 = *(const float4*)&hidden[lane * 8];
      float4 h1 = *(const float4*)&hidden[lane * 8 + 4];
      float s = w0.x * h0.x + w0.y * h0.y + w0.z * h0.z + w0.w * h0.w +
                w1.x * h1.x + w1.y * h1.y + w1.z * h1.z + w1.w * h1.w;
      s = wsum64(s);
      if (lane == 0) es2[j] = dinv[j] * (s + msgb[j]);
    }
  }
  gridbar(bar, 2);

  //================ P3: GCN1 gather (2 rows per wave) ================
  {
    int wg = blk * 16 + wave;  // 0..4095
#pragma unroll
    for (int rr = 0; rr < 2; rr++) {
      int i = wg * 2 + rr;
      int ci = min(cnt[i], CSR_CAP);
      float di = dinv[i];
      float a0 = 0.0f, a1 = 0.0f;
      for (int e = lane; e < ci; e += 64) {
        int s = csr[i * CSR_CAP + e];
        a0 += xs2[s];
        a1 += es2[s];
      }
      float f0 = (wsum64(a0) + di * xs2[i]) * di;
      float f1 = (wsum64(a1) + di * es2[i]) * di;
      if (lane < 16) {
        float gv = fmaxf(f0 * g1w[lane] + f1 * g1w[16 + lane] + g1b[lane], 0.0f);
        gbuf2[i * 16 + lane] = di * gv;
      }
    }
  }
  gridbar(bar, 3);

  //================ P4: GCN2 gather + wstats + MFMA scores + sum-exp ================
  {
    int rowbase = blk * 32;
    {  // gather 32 V rows: 16 waves x 2 rows; lanes = 4 edge-groups x 16 cols
      int eq = lane >> 4, c = lane & 15;
#pragma unroll
      for (int rr = 0; rr < 2; rr++) {
        int il = wave * 2 + rr;
        int i = rowbase + il;
        int ci = min(cnt[i], CSR_CAP);
        float di = dinv[i];
        float acc = (eq == 0) ? di * gbuf2[i * 16 + c] : 0.0f;
        for (int e = eq; e < ci; e += 4) {
          int s = csr[i * CSR_CAP + e];
          acc += gbuf2[s * 16 + c];
        }
        acc *= di;
        acc += __shfl_xor(acc, 16, 64);
        acc += __shfl_xor(acc, 32, 64);
        if (eq == 0) {
          sm.mg.vf[il * 16 + c] = acc;
          sm.mg.vbf[il * 16 + c] = f2bf(acc);
        }
      }
    }
    __syncthreads();
    if (t < 272) {  // wstats reduce from per-block partials
      int bq = t / 17, k = t - bq * 17;
      float s = 0.0f;
      for (int b = bq; b < 256; b += 16) s += wpart[b * 17 + k];
      sm.mg.wp[bq][k] = s;
    }
    __syncthreads();
    if (t < 17) {
      float s = 0.0f;
#pragma unroll
      for (int q = 0; q < 16; q++) s += sm.mg.wp[q][t];
      sm.mg.wsf[t] = s;
    }
    __syncthreads();
    float myMean = 0.0f;
    if (t < 32) {
      float dot = 0.0f;
#pragma unroll
      for (int c = 0; c < 16; c++) dot += sm.mg.vf[t * 16 + c] * sm.mg.wsf[c];
      myMean = (dot + sm.mg.wsf[16]) * (1.0f / 8192.0f);
    }
    {  // scores via MFMA + direct sum-of-exp; each wave owns a 512-col slice
      int quad = lane >> 4, n = lane & 15;
      int k8 = quad * 8;
      short8 za = {0, 0, 0, 0, 0, 0, 0, 0};
      short8 a1 = za, a2 = za;
      if (quad < 2) {  // K padded 16->32
        a1 = *(const short8*)&sm.mg.vbf[n * 16 + k8];
        a2 = *(const short8*)&sm.mg.vbf[(16 + n) * 16 + k8];
      }
      float sacc[8];
#pragma unroll
      for (int q = 0; q < 8; q++) sacc[q] = 0.0f;
      for (int tp = 0; tp < 16; tp++) {
        int col1 = wave * 512 + tp * 32 + n;
        int col2 = col1 + 16;
        short8 b1 = za, b2 = za;
        if (quad < 2) {
          b1 = *(const short8*)&w2t[col1 * 16 + k8];
          b2 = *(const short8*)&w2t[col2 * 16 + k8];
        }
        float bb1 = g2b[col1], bb2 = g2b[col2];
        float4v c1 = {bb1, bb1, bb1, bb1};
        float4v c2 = {bb2, bb2, bb2, bb2};
        float4v s11 = __builtin_amdgcn_mfma_f32_16x16x32_bf16(a1, b1, c1, 0, 0, 0);
        float4v s21 = __builtin_amdgcn_mfma_f32_16x16x32_bf16(a2, b1, c1, 0, 0, 0);
        float4v s12 = __builtin_amdgcn_mfma_f32_16x16x32_bf16(a1, b2, c2, 0, 0, 0);
        float4v s22 = __builtin_amdgcn_mfma_f32_16x16x32_bf16(a2, b2, c2, 0, 0, 0);
#pragma unroll
        for (int r = 0; r < 4; r++) {
          sacc[r]     += __expf(s11[r]) + __expf(s12[r]);
          sacc[4 + r] += __expf(s21[r]) + __expf(s22[r]);
        }
      }
#pragma unroll
      for (int q = 0; q < 8; q++) {
        int rl = (q >> 2) * 16 + quad * 4 + (q & 3);  // C/D row = quad*4+reg (+16 for A2)
        sm.mg.pl[rl * 256 + wave * 16 + n] = sacc[q];
      }
    }
    __syncthreads();
    {  // reduce 256 partials per row
      int r = t >> 5, seg = t & 31;
      int base = r * 256 + seg * 8;
      float ll = 0.0f;
#pragma unroll
      for (int i = 0; i < 8; i++) ll += sm.mg.pl[base + i];
      sm.mg.sl[r * 32 + seg] = ll;
    }
    __syncthreads();
    if (t < 32) {
      float ll = 0.0f;
#pragma unroll
      for (int i = 0; i < 32; i++) ll += sm.mg.sl[t * 32 + i];
      out[256 + rowbase + t] = myMean - __logf(ll);
    }
  }
}

extern "C" void kernel_launch(void* const* d_in, const int* in_sizes, int n_in,
                              void* d_out, int out_size, void* d_ws, size_t ws_size,
                              hipStream_t stream) {
  const float* x     = (const float*)d_in[0];
  const float* x_msg = (const float*)d_in[1];
  const int*   edges = (const int*)d_in[2];
  const int*   action= (const int*)d_in[3];
  const float* c1w   = (const float*)d_in[4];
  const float* c1b   = (const float*)d_in[5];
  const float* c2w   = (const float*)d_in[6];
  const float* c2b   = (const float*)d_in[7];
  const float* fcw   = (const float*)d_in[8];
  const float* fcb   = (const float*)d_in[9];
  const float* muw   = (const float*)d_in[10];
  const float* mub   = (const float*)d_in[11];
  const float* msgw  = (const float*)d_in[12];
  const float* msgb  = (const float*)d_in[13];
  const float* g1w   = (const float*)d_in[14];
  const float* g1b   = (const float*)d_in[15];
  const float* g2w   = (const float*)d_in[16];
  const float* g2b   = (const float*)d_in[17];
  float* out = (float*)d_out;  // reference outputs are fp32

  float* ws     = (float*)d_ws;
  float* h1024  = ws;                    // 262144
  float* hidden = ws + 262144;           // 131072
  float* es2    = ws + 393216;           // 8192
  float* dinv   = ws + 401408;           // 8192
  float* xs2    = ws + 409600;           // 8192
  float* gbuf2  = ws + 417792;           // 131072
  float* wpart  = ws + 548864;           // 4352
  unsigned short* w2t = (unsigned short*)(ws + 553216);   // 131072 bf16
  int*   cnt    = (int*)(ws + 618752);   // 8192 ints
  unsigned short* csr = (unsigned short*)(ws + 626944);   // 8192*128 ushort (512KB)
  int*   bar    = (int*)(ws + 758016);   // 16

  k_init<<<33, 256, 0, stream>>>(action, cnt, bar, out);
  k_mega<<<NBLK, NTHR, 0, stream>>>(x, x_msg, edges, c1w, c1b, c2w, c2b, fcw, fcb,
                                    muw, mub, msgw, msgb, g1w, g1b, g2w, g2b, action,
                                    h1024, hidden, es2, dinv, xs2, gbuf2, wpart,
                                    w2t, cnt, csr, bar, out);
}

// Round 8
// 257.890 us; speedup vs baseline: 1.4966x; 1.4966x over previous
//
#include <hip/hip_runtime.h>
#include <hip/hip_bf16.h>

// Problem constants
#define NB 256
#define NACT 21
#define NA 8192
#define NE 262144
#define CSR_CAP 128

typedef __attribute__((ext_vector_type(8))) short short8;
typedef __attribute__((ext_vector_type(4))) float float4v;

__device__ inline float wsum64(float v) {
#pragma unroll
  for (int m = 32; m > 0; m >>= 1) v += __shfl_xor(v, m, 64);
  return v;
}

__device__ inline unsigned short f2bf(float f) {
  union { __hip_bfloat16 h; unsigned short u; } cv;
  cv.h = __float2bfloat16(f);
  return cv.u;
}

// Grid barrier: release-add, RELAXED poll, final acquire. Bounded spin ->
// wrong results (caught by absmax) instead of hang on failure.
__device__ inline void gridbar(int* bar, int idx, int nblk) {
  __syncthreads();
  if (threadIdx.x == 0) {
    __hip_atomic_fetch_add(&bar[idx], 1, __ATOMIC_RELEASE, __HIP_MEMORY_SCOPE_AGENT);
    int guard = 0;
    while (__hip_atomic_load(&bar[idx], __ATOMIC_RELAXED, __HIP_MEMORY_SCOPE_AGENT) < nblk &&
           guard < (1 << 22)) {
      guard++;
      __builtin_amdgcn_s_sleep(8);
    }
    (void)__hip_atomic_load(&bar[idx], __ATOMIC_ACQUIRE, __HIP_MEMORY_SCOPE_AGENT);
  }
  __syncthreads();
}

// ---------------- dispatch 1: zero cnt/bar + action passthrough ----------------
__global__ void k_init(const int* action, int* cnt, int* bar, float* out) {
  int i = blockIdx.x * 256 + threadIdx.x;  // 33*256 = 8448 threads
  if (i < NA) cnt[i] = 0;
  if (i < 16) bar[i] = 0;
  if (i < NB) out[i] = (float)action[i];
}

// ---------------- kA: conv (blocks 0..255) || CSR + W2 prep (blocks 256..511) ----------------
__global__ __launch_bounds__(512, 4) void kA(
    const float* __restrict__ x, const int* __restrict__ edges,
    const float* __restrict__ c1w, const float* __restrict__ c1b,
    const float* __restrict__ c2w, const float* __restrict__ c2b,
    const float* __restrict__ g2w, const float* __restrict__ g2b,
    float* h1024, unsigned short* w2t, float* wpart, int* cnt, int* csr) {
  union SM {
    struct { float xs[845]; float w1s[1440]; float c1s[1152]; float w2s[64 * 73]; } cv;
    struct { float red[32][17]; float b2s[32]; } w2;
  };
  __shared__ __align__(16) union SM sm;
  int t = threadIdx.x, blk = blockIdx.x;

  if (blk >= 256) {
    int b2 = blk - 256;  // 0..255
    {  // CSR: 2 edges per thread
      int gid = b2 * 512 + t;
      int s = edges[2 * gid], d = edges[2 * gid + 1];
      int slot = atomicAdd(&cnt[d], 1);
      if (slot < CSR_CAP) csr[d * CSR_CAP + slot] = s;
      int gid2 = gid + 131072;
      s = edges[2 * gid2]; d = edges[2 * gid2 + 1];
      slot = atomicAdd(&cnt[d], 1);
      if (slot < CSR_CAP) csr[d * CSR_CAP + slot] = s;
    }
    {  // W2 transpose->bf16 + per-block column/bias partials
      int jj = t >> 4, k = t & 15;
      int j = b2 * 32 + jj;
      float w = g2w[k * 8192 + j];
      w2t[j * 16 + k] = f2bf(w);
      sm.w2.red[jj][k] = w;
      if (t < 32) sm.w2.b2s[t] = g2b[b2 * 32 + t];
      __syncthreads();
      if (t < 16) {
        float s = 0.0f;
#pragma unroll
        for (int q = 0; q < 32; q++) s += sm.w2.red[q][t];
        wpart[b2 * 17 + t] = s;
      } else if (t == 16) {
        float s = 0.0f;
#pragma unroll
        for (int q = 0; q < 32; q++) s += sm.w2.b2s[q];
        wpart[b2 * 17 + 16] = s;
      }
    }
    return;
  }
  // conv: fused conv1+conv2, one block per image
  for (int i = t; i < 845; i += 512) sm.cv.xs[i] = x[blk * 845 + i];
  for (int i = t; i < 1440; i += 512) sm.cv.w1s[i] = c1w[i];
  __syncthreads();
  for (int idx = t; idx < 1152; idx += 512) {
    int oc = idx / 36, p = idx - oc * 36;
    int oy = p / 6, ox = p - oy * 6;
    float acc = c1b[oc];
    const float* wp = &sm.cv.w1s[oc * 45];
#pragma unroll
    for (int ic = 0; ic < 5; ic++)
#pragma unroll
      for (int ky = 0; ky < 3; ky++)
#pragma unroll
        for (int kx = 0; kx < 3; kx++)
          acc += sm.cv.xs[ic * 169 + (oy * 2 + ky) * 13 + ox * 2 + kx] * wp[ic * 9 + ky * 3 + kx];
    sm.cv.c1s[idx] = fmaxf(acc, 0.0f);
  }
  int p = t & 15, oc2 = t >> 4;  // oc2 0..31, 2 output channels each
  int oy = p >> 2, ox = p & 3;
  float a0 = c2b[oc2 * 2 + 0], a1 = c2b[oc2 * 2 + 1];
  for (int icb = 0; icb < 32; icb += 8) {
    __syncthreads();
    for (int i = t; i < 4608; i += 512) {
      int oc = i / 72, r = i - oc * 72;
      sm.cv.w2s[oc * 73 + r] = c2w[oc * 288 + icb * 9 + r];
    }
    __syncthreads();
#pragma unroll
    for (int ic = 0; ic < 8; ic++) {
#pragma unroll
      for (int ky = 0; ky < 3; ky++) {
#pragma unroll
        for (int kx = 0; kx < 3; kx++) {
          float cvv = sm.cv.c1s[(icb + ic) * 36 + (oy + ky) * 6 + ox + kx];
          int wi = ic * 9 + ky * 3 + kx;
          a0 += cvv * sm.cv.w2s[(oc2 * 2 + 0) * 73 + wi];
          a1 += cvv * sm.cv.w2s[(oc2 * 2 + 1) * 73 + wi];
        }
      }
    }
  }
  float* hp = &h1024[blk * 1024];
  hp[(oc2 * 2 + 0) * 16 + p] = fmaxf(a0, 0.0f);
  hp[(oc2 * 2 + 1) * 16 + p] = fmaxf(a1, 0.0f);
}

// ---------------- kB: dinv/xs2 + FC (8x32 tiles) | bar | head + enc ----------------
__global__ __launch_bounds__(512, 4) void kB(
    const int* __restrict__ cnt, const float* __restrict__ x_msg,
    const float* __restrict__ h1024, const float* __restrict__ fcw,
    const float* __restrict__ fcb, const float* __restrict__ muw,
    const float* __restrict__ mub, const int* __restrict__ action,
    const float* __restrict__ msgw, const float* __restrict__ msgb,
    float* hidden, float* dinv, float* xs2, float* es2, int* bar, float* out) {
  union SM {
    struct { float As[8][132]; float Bs[32][132]; } fc;
    struct { float muT[10752]; float hrows[2048]; } hd;
  };
  __shared__ __align__(16) union SM sm;
  int t = threadIdx.x, blk = blockIdx.x;
  int wave = t >> 6, lane = t & 63;
  int gid = blk * 512 + t;

  if (gid < NA) {
    float d = rsqrtf((float)cnt[gid] + 1.0f);
    dinv[gid] = d;
    xs2[gid] = d * x_msg[gid];
  }
  {  // FC: block owns 8x32 output tile; lane-pair K-split; no atomics
    int rb = (blk >> 4) * 8, cb = (blk & 15) * 32;
    int r = t >> 6;                       // wave id = row 0..7
    int c = (t & 63) >> 1, half = t & 1;  // 32 cols, lane-pair K split
    float acc = 0.0f;
    for (int kb = 0; kb < 1024; kb += 128) {
      __syncthreads();
      if (t < 256) {  // A: 8x128 = 1024 floats
        int ar = t >> 5, ak = (t & 31) * 4;
        *(float4*)&sm.fc.As[ar][ak] = *(const float4*)&h1024[(rb + ar) * 1024 + kb + ak];
      }
      {  // B: 32x128 = 4096 floats, 8 per thread
        int br = t >> 4, bk = (t & 15) * 8;
        *(float4*)&sm.fc.Bs[br][bk] = *(const float4*)&fcw[(cb + br) * 1024 + kb + bk];
        *(float4*)&sm.fc.Bs[br][bk + 4] = *(const float4*)&fcw[(cb + br) * 1024 + kb + bk + 4];
      }
      __syncthreads();
      int k0 = half * 64;
#pragma unroll 16
      for (int kk = 0; kk < 64; kk += 4) {
        float4 a = *(const float4*)&sm.fc.As[r][k0 + kk];
        float4 b = *(const float4*)&sm.fc.Bs[c][k0 + kk];
        acc += a.x * b.x + a.y * b.y + a.z * b.z + a.w * b.w;
      }
    }
    acc += __shfl_xor(acc, 1, 64);
    if (half == 0) hidden[(rb + r) * 512 + cb + c] = fmaxf(acc + fcb[cb + c], 0.0f);
  }
  gridbar(bar, 0, 512);
  if (blk < 64) {  // head: 4 batch rows per block
    int b0 = blk * 4;
    for (int i = t; i < 10752; i += 512) {
      int a = i >> 9, k = i & 511;
      sm.hd.muT[k * 21 + a] = muw[i];
    }
    for (int i = t; i < 2048; i += 512) sm.hd.hrows[i] = hidden[b0 * 512 + i];
    __syncthreads();
    if (wave < 4) {
      int b = b0 + wave;
      float logit = -1e30f;
      if (lane < NACT) {
        float acc = mub[lane];
        const float* hr = &sm.hd.hrows[wave * 512];
        for (int k = 0; k < 512; k++) acc += hr[k] * sm.hd.muT[k * 21 + lane];
        logit = acc;
      }
      float m = logit;
#pragma unroll
      for (int s = 32; s > 0; s >>= 1) m = fmaxf(m, __shfl_xor(m, s, 64));
      float e = (lane < NACT) ? __expf(logit - m) : 0.0f;
      float se = wsum64(e);
      float swl = wsum64(e * logit);
      float lse = m + __logf(se);
      int act = action[b];
      if (lane == 0) out[8704 + b] = lse - swl / se;   // entropy
      if (lane == act) out[8448 + b] = logit - lse;    // log_prob
    }
  } else {  // enc: es2[j] = dinv[j] * (hidden[0].msg_w[j] + msgb[j])
    int wg = (blk - 64) * 8 + wave;  // 0..3583
    for (int j = wg; j < NA; j += 3584) {
      const float* wp = &msgw[j * 512 + lane * 8];
      float4 w0 = *(const float4*)(wp);
      float4 w1 = *(const float4*)(wp + 4);
      float4 h0 = *(const float4*)&hidden[lane * 8];
      float4 h1 = *(const float4*)&hidden[lane * 8 + 4];
      float s = w0.x * h0.x + w0.y * h0.y + w0.z * h0.z + w0.w * h0.w +
                w1.x * h1.x + w1.y * h1.y + w1.z * h1.z + w1.w * h1.w;
      s = wsum64(s);
      if (lane == 0) es2[j] = dinv[j] * (s + msgb[j]);
    }
  }
}

// ---------------- kC: GCN1 | bar | GCN2 gather + wstats + MFMA + sum-exp ----------------
__global__ __launch_bounds__(512, 4) void kC(
    const int* __restrict__ cnt, const int* __restrict__ csr,
    const float* __restrict__ dinv, const float* __restrict__ xs2,
    const float* __restrict__ es2, const float* __restrict__ g1w,
    const float* __restrict__ g1b, const float* __restrict__ wpart,
    const unsigned short* __restrict__ w2t, const float* __restrict__ g2b,
    float* gbuf2, int* bar, float* out) {
  __shared__ __align__(16) unsigned short vbf[256];
  __shared__ float vf[256];
  __shared__ float pl[2048];
  __shared__ float sl[512];
  __shared__ float wp[16][17];
  __shared__ float wsf[17];
  int t = threadIdx.x, blk = blockIdx.x;
  int wave = t >> 6, lane = t & 63;

  {  // GCN1: 2 rows per wave; gbuf2[i] = dinv[i] * g[i]
    int wg = blk * 8 + wave;  // 0..4095
#pragma unroll
    for (int rr = 0; rr < 2; rr++) {
      int i = wg * 2 + rr;
      int ci = min(cnt[i], CSR_CAP);
      float di = dinv[i];
      float a0 = 0.0f, a1 = 0.0f;
      for (int e = lane; e < ci; e += 64) {
        int s = csr[i * CSR_CAP + e];
        a0 += xs2[s];
        a1 += es2[s];
      }
      float f0 = (wsum64(a0) + di * xs2[i]) * di;
      float f1 = (wsum64(a1) + di * es2[i]) * di;
      if (lane < 16) {
        float gv = fmaxf(f0 * g1w[lane] + f1 * g1w[16 + lane] + g1b[lane], 0.0f);
        gbuf2[i * 16 + lane] = di * gv;
      }
    }
  }
  gridbar(bar, 1, 512);
  int rowbase = blk * 16;
  {  // GCN2 gather 16 V rows: 8 waves x 2 rows; lanes = 4 edge-groups x 16 cols
    int eq = lane >> 4, c = lane & 15;
#pragma unroll
    for (int rr = 0; rr < 2; rr++) {
      int il = wave * 2 + rr;
      int i = rowbase + il;
      int ci = min(cnt[i], CSR_CAP);
      float di = dinv[i];
      float acc = (eq == 0) ? di * gbuf2[i * 16 + c] : 0.0f;
      for (int e = eq; e < ci; e += 4) {
        int s = csr[i * CSR_CAP + e];
        acc += gbuf2[s * 16 + c];
      }
      acc *= di;
      acc += __shfl_xor(acc, 16, 64);
      acc += __shfl_xor(acc, 32, 64);
      if (eq == 0) {
        vf[il * 16 + c] = acc;
        vbf[il * 16 + c] = f2bf(acc);
      }
    }
  }
  __syncthreads();
  if (t < 272) {  // wstats reduce from per-block partials (256 producers)
    int bq = t / 17, k = t - bq * 17;
    float s = 0.0f;
    for (int b = bq; b < 256; b += 16) s += wpart[b * 17 + k];
    wp[bq][k] = s;
  }
  __syncthreads();
  if (t < 17) {
    float s = 0.0f;
#pragma unroll
    for (int q = 0; q < 16; q++) s += wp[q][t];
    wsf[t] = s;
  }
  __syncthreads();
  float myMean = 0.0f;
  if (t < 16) {
    float dot = 0.0f;
#pragma unroll
    for (int c = 0; c < 16; c++) dot += vf[t * 16 + c] * wsf[c];
    myMean = (dot + wsf[16]) * (1.0f / 8192.0f);
  }
  {  // scores via MFMA + direct sum-of-exp; each wave owns a 1024-col slice
    int quad = lane >> 4, n = lane & 15;
    int k8 = quad * 8;
    short8 za = {0, 0, 0, 0, 0, 0, 0, 0};
    short8 a1 = za;
    if (quad < 2) a1 = *(const short8*)&vbf[n * 16 + k8];  // K padded 16->32
    float sacc[4];
#pragma unroll
    for (int q = 0; q < 4; q++) sacc[q] = 0.0f;
    for (int tp = 0; tp < 32; tp++) {
      int col1 = wave * 1024 + tp * 32 + n;
      int col2 = col1 + 16;
      short8 b1 = za, b2 = za;
      if (quad < 2) {
        b1 = *(const short8*)&w2t[col1 * 16 + k8];
        b2 = *(const short8*)&w2t[col2 * 16 + k8];
      }
      float bb1 = g2b[col1], bb2 = g2b[col2];
      float4v c1 = {bb1, bb1, bb1, bb1};
      float4v c2 = {bb2, bb2, bb2, bb2};
      float4v s11 = __builtin_amdgcn_mfma_f32_16x16x32_bf16(a1, b1, c1, 0, 0, 0);
      float4v s12 = __builtin_amdgcn_mfma_f32_16x16x32_bf16(a1, b2, c2, 0, 0, 0);
#pragma unroll
      for (int r = 0; r < 4; r++) sacc[r] += __expf(s11[r]) + __expf(s12[r]);
    }
#pragma unroll
    for (int q = 0; q < 4; q++) {
      int rl = quad * 4 + q;  // C/D row = quad*4+reg
      pl[rl * 128 + wave * 16 + n] = sacc[q];
    }
  }
  __syncthreads();
  {  // reduce 128 partials per row: 16 rows x 32 segs x 4
    int r = t >> 5, seg = t & 31;
    int base = r * 128 + seg * 4;
    float ll = pl[base] + pl[base + 1] + pl[base + 2] + pl[base + 3];
    sl[r * 32 + seg] = ll;
  }
  __syncthreads();
  if (t < 16) {
    float ll = 0.0f;
#pragma unroll
    for (int i = 0; i < 32; i++) ll += sl[t * 32 + i];
    out[256 + rowbase + t] = myMean - __logf(ll);
  }
}

extern "C" void kernel_launch(void* const* d_in, const int* in_sizes, int n_in,
                              void* d_out, int out_size, void* d_ws, size_t ws_size,
                              hipStream_t stream) {
  const float* x     = (const float*)d_in[0];
  const float* x_msg = (const float*)d_in[1];
  const int*   edges = (const int*)d_in[2];
  const int*   action= (const int*)d_in[3];
  const float* c1w   = (const float*)d_in[4];
  const float* c1b   = (const float*)d_in[5];
  const float* c2w   = (const float*)d_in[6];
  const float* c2b   = (const float*)d_in[7];
  const float* fcw   = (const float*)d_in[8];
  const float* fcb   = (const float*)d_in[9];
  const float* muw   = (const float*)d_in[10];
  const float* mub   = (const float*)d_in[11];
  const float* msgw  = (const float*)d_in[12];
  const float* msgb  = (const float*)d_in[13];
  const float* g1w   = (const float*)d_in[14];
  const float* g1b   = (const float*)d_in[15];
  const float* g2w   = (const float*)d_in[16];
  const float* g2b   = (const float*)d_in[17];
  float* out = (float*)d_out;  // reference outputs are fp32

  float* ws     = (float*)d_ws;
  float* h1024  = ws;                    // 262144
  float* hidden = ws + 262144;           // 131072
  float* es2    = ws + 393216;           // 8192
  float* dinv   = ws + 401408;           // 8192
  float* xs2    = ws + 409600;           // 8192
  float* gbuf2  = ws + 417792;           // 131072
  float* wpart  = ws + 548864;           // 4352
  unsigned short* w2t = (unsigned short*)(ws + 553216);  // 131072 bf16
  int*   cnt    = (int*)(ws + 618752);   // 8192
  int*   csr    = (int*)(ws + 626944);   // 1048576
  int*   bar    = (int*)(ws + 1675520);  // 16

  k_init<<<33, 256, 0, stream>>>(action, cnt, bar, out);
  kA<<<512, 512, 0, stream>>>(x, edges, c1w, c1b, c2w, c2b, g2w, g2b,
                              h1024, w2t, wpart, cnt, csr);
  kB<<<512, 512, 0, stream>>>(cnt, x_msg, h1024, fcw, fcb, muw, mub, action,
                              msgw, msgb, hidden, dinv, xs2, es2, bar, out);
  kC<<<512, 512, 0, stream>>>(cnt, csr, dinv, xs2, es2, g1w, g1b, wpart,
                              w2t, g2b, gbuf2, bar, out);
}

// Round 10
// 221.795 us; speedup vs baseline: 1.7401x; 1.1627x over previous
//
#include <hip/hip_runtime.h>
#include <hip/hip_bf16.h>

// Problem constants
#define NB 256
#define NACT 21
#define NA 8192
#define NE 262144
#define CSR_CAP 128
#define NBLK 256
#define NTHR 512
#define LOG2E 1.44269504f

#if __has_builtin(__builtin_amdgcn_exp2f)
#define EXP2F(x) __builtin_amdgcn_exp2f(x)
#else
#define EXP2F(x) exp2f(x)
#endif

typedef __attribute__((ext_vector_type(8))) short short8;
typedef __attribute__((ext_vector_type(4))) float float4v;

__device__ inline float wsum64(float v) {
#pragma unroll
  for (int m = 32; m > 0; m >>= 1) v += __shfl_xor(v, m, 64);
  return v;
}

__device__ inline unsigned short f2bf(float f) {
  union { __hip_bfloat16 h; unsigned short u; } cv;
  cv.h = __float2bfloat16(f);
  return cv.u;
}

// Grid barrier: release-add, RELAXED poll, final acquire. Bounded spin ->
// wrong results (caught by absmax) instead of hang on failure.
__device__ inline void gridbar(int* bar, int idx) {
  __syncthreads();
  if (threadIdx.x == 0) {
    __hip_atomic_fetch_add(&bar[idx], 1, __ATOMIC_RELEASE, __HIP_MEMORY_SCOPE_AGENT);
    int guard = 0;
    while (__hip_atomic_load(&bar[idx], __ATOMIC_RELAXED, __HIP_MEMORY_SCOPE_AGENT) < NBLK &&
           guard < (1 << 22)) {
      guard++;
      __builtin_amdgcn_s_sleep(8);
    }
    (void)__hip_atomic_load(&bar[idx], __ATOMIC_ACQUIRE, __HIP_MEMORY_SCOPE_AGENT);
  }
  __syncthreads();
}

// ---------------- dispatch 1: zero cnt/bar + action passthrough ----------------
__global__ void k_init(const int* action, int* cnt, int* bar, float* out) {
  int i = blockIdx.x * 256 + threadIdx.x;  // 33*256 = 8448 threads
  if (i < NA) cnt[i] = 0;
  if (i < 16) bar[i] = 0;
  if (i < NB) out[i] = (float)action[i];
}

// ---------------- dispatch 2: everything, 256 blocks x 512 threads ----------------
__global__ __launch_bounds__(NTHR, 2) void k_mega(
    const float* __restrict__ x, const float* __restrict__ x_msg,
    const int* __restrict__ edges,
    const float* __restrict__ c1w, const float* __restrict__ c1b,
    const float* __restrict__ c2w, const float* __restrict__ c2b,
    const float* __restrict__ fcw, const float* __restrict__ fcb,
    const float* __restrict__ muw, const float* __restrict__ mub,
    const float* __restrict__ msgw, const float* __restrict__ msgb,
    const float* __restrict__ g1w, const float* __restrict__ g1b,
    const float* __restrict__ g2w, const float* __restrict__ g2b,
    unsigned short* h1024bf, unsigned short* fcwbf, float* hidden,
    float* es2, float* dinv, float* xs2, float* gbuf2, float* wpart,
    unsigned short* w2t, int* cnt, int* csr, int* bar, float* out) {
  union SM {
    struct { float xs[845]; float w1s[1440]; float c1s[1152]; float w2s[64 * 73]; } cv;
    struct { float red[2][4][256]; } fc;                       // 8 KB
    struct { float muT[10752]; float hrows[2048]; } hd;        // 51.2 KB
    struct { unsigned short vbf[512]; float vf[512]; float pl[4096]; float sl[256];
             float wp[16][17]; float wsf[17]; } mg;            // ~21.5 KB
  };
  __shared__ __align__(16) union SM sm;
  __shared__ float w2red[32][17];
  __shared__ float w2b2s[32];
  int t = threadIdx.x, blk = blockIdx.x;
  int wave = t >> 6, lane = t & 63;

  //================ P0: CSR + fcw->bf16 + W2 prep + conv(->bf16) ================
  {  // CSR: 2 edges per thread
    int gid = blk * NTHR + t;
    int s = edges[2 * gid], d = edges[2 * gid + 1];
    int slot = atomicAdd(&cnt[d], 1);
    if (slot < CSR_CAP) csr[d * CSR_CAP + slot] = s;
    int gid2 = gid + 131072;
    s = edges[2 * gid2]; d = edges[2 * gid2 + 1];
    slot = atomicAdd(&cnt[d], 1);
    if (slot < CSR_CAP) csr[d * CSR_CAP + slot] = s;
  }
  {  // fcw -> bf16 (2048 elems per block)
    int base = blk * 2048 + t * 4;
    float4 v = *(const float4*)&fcw[base];
    fcwbf[base + 0] = f2bf(v.x); fcwbf[base + 1] = f2bf(v.y);
    fcwbf[base + 2] = f2bf(v.z); fcwbf[base + 3] = f2bf(v.w);
  }
  {  // W2 transpose->bf16 + per-block column/bias partials
    int jj = t >> 4, k = t & 15;
    int j = blk * 32 + jj;
    float w = g2w[k * 8192 + j];
    w2t[j * 16 + k] = f2bf(w);
    w2red[jj][k] = w;
    if (t < 32) w2b2s[t] = g2b[blk * 32 + t];
    __syncthreads();
    if (t < 16) {
      float s = 0.0f;
#pragma unroll
      for (int q = 0; q < 32; q++) s += w2red[q][t];
      wpart[blk * 17 + t] = s;
    } else if (t == 16) {
      float s = 0.0f;
#pragma unroll
      for (int q = 0; q < 32; q++) s += w2b2s[q];
      wpart[blk * 17 + 16] = s;
    }
    __syncthreads();
  }
  {  // fused conv1+conv2, one block per image; output bf16
    for (int i = t; i < 845; i += NTHR) sm.cv.xs[i] = x[blk * 845 + i];
    for (int i = t; i < 1440; i += NTHR) sm.cv.w1s[i] = c1w[i];
    __syncthreads();
    for (int idx = t; idx < 1152; idx += NTHR) {
      int oc = idx / 36, p = idx - oc * 36;
      int oy = p / 6, ox = p - oy * 6;
      float acc = c1b[oc];
      const float* wp = &sm.cv.w1s[oc * 45];
#pragma unroll
      for (int ic = 0; ic < 5; ic++)
#pragma unroll
        for (int ky = 0; ky < 3; ky++)
#pragma unroll
          for (int kx = 0; kx < 3; kx++)
            acc += sm.cv.xs[ic * 169 + (oy * 2 + ky) * 13 + ox * 2 + kx] * wp[ic * 9 + ky * 3 + kx];
      sm.cv.c1s[idx] = fmaxf(acc, 0.0f);
    }
    int p = t & 15, oc2 = t >> 4;  // 2 output channels each
    int oy = p >> 2, ox = p & 3;
    float a0 = c2b[oc2 * 2 + 0], a1 = c2b[oc2 * 2 + 1];
    for (int icb = 0; icb < 32; icb += 8) {
      __syncthreads();
      for (int i = t; i < 4608; i += NTHR) {
        int oc = i / 72, r = i - oc * 72;
        sm.cv.w2s[oc * 73 + r] = c2w[oc * 288 + icb * 9 + r];
      }
      __syncthreads();
#pragma unroll
      for (int ic = 0; ic < 8; ic++) {
#pragma unroll
        for (int ky = 0; ky < 3; ky++) {
#pragma unroll
          for (int kx = 0; kx < 3; kx++) {
            float cvv = sm.cv.c1s[(icb + ic) * 36 + (oy + ky) * 6 + ox + kx];
            int wi = ic * 9 + ky * 3 + kx;
            a0 += cvv * sm.cv.w2s[(oc2 * 2 + 0) * 73 + wi];
            a1 += cvv * sm.cv.w2s[(oc2 * 2 + 1) * 73 + wi];
          }
        }
      }
    }
    unsigned short* hp = &h1024bf[blk * 1024];
    hp[(oc2 * 2 + 0) * 16 + p] = f2bf(fmaxf(a0, 0.0f));
    hp[(oc2 * 2 + 1) * 16 + p] = f2bf(fmaxf(a1, 0.0f));
  }
  gridbar(bar, 0);

  //================ P1: dinv/xs2 + FC via bf16 MFMA (2 tiles/block, K-split 4) ================
  if (blk < 16) {
    int gid = blk * NTHR + t;
    float d = rsqrtf((float)cnt[gid] + 1.0f);
    dinv[gid] = d;
    xs2[gid] = d * x_msg[gid];
  }
  {
    int wtile = wave >> 2;             // 0/1: which of the block's 2 tiles
    int kslice = wave & 3;             // K-split: 256 per slice
    int tl = blk * 2 + wtile;          // tile 0..511
    int tr = tl >> 5, tc = tl & 31;    // 16 row-tiles x 32 col-tiles
    int m = lane & 15, quad = lane >> 4;
    const unsigned short* ap = &h1024bf[(tr * 16 + m) * 1024 + kslice * 256 + quad * 8];
    const unsigned short* bp = &fcwbf[(tc * 16 + m) * 1024 + kslice * 256 + quad * 8];
    float4v acc = {0.0f, 0.0f, 0.0f, 0.0f};
#pragma unroll
    for (int i = 0; i < 8; i++) {
      short8 a = *(const short8*)(ap + i * 32);
      short8 b = *(const short8*)(bp + i * 32);
      acc = __builtin_amdgcn_mfma_f32_16x16x32_bf16(a, b, acc, 0, 0, 0);
    }
    __syncthreads();  // protect union (conv phase done for this block)
#pragma unroll
    for (int r = 0; r < 4; r++)
      sm.fc.red[wtile][kslice][(quad * 4 + r) * 16 + m] = acc[r];
    __syncthreads();
    {  // reduce 4 K-slices + bias + relu -> hidden
      int wt = t >> 8, e = t & 255;
      float s = sm.fc.red[wt][0][e] + sm.fc.red[wt][1][e] + sm.fc.red[wt][2][e] + sm.fc.red[wt][3][e];
      int tl2 = blk * 2 + wt;
      int gr = (tl2 >> 5) * 16 + (e >> 4);
      int gc = (tl2 & 31) * 16 + (e & 15);
      hidden[gr * 512 + gc] = fmaxf(s + fcb[gc], 0.0f);
    }
  }
  gridbar(bar, 1);

  //================ P2: head (blocks 0..63) | enc (blocks 64..255) ================
  if (blk < 64) {
    int b0 = blk * 4;
    for (int i = t; i < 10752; i += NTHR) {
      int a = i >> 9, k = i & 511;
      sm.hd.muT[k * 21 + a] = muw[i];
    }
    for (int i = t; i < 2048; i += NTHR) sm.hd.hrows[i] = hidden[b0 * 512 + i];
    __syncthreads();
    if (wave < 4) {
      int b = b0 + wave;
      float logit = -1e30f;
      if (lane < NACT) {
        float acc = mub[lane];
        const float* hr = &sm.hd.hrows[wave * 512];
        for (int k = 0; k < 512; k++) acc += hr[k] * sm.hd.muT[k * 21 + lane];
        logit = acc;
      }
      float m = logit;
#pragma unroll
      for (int s = 32; s > 0; s >>= 1) m = fmaxf(m, __shfl_xor(m, s, 64));
      float e = (lane < NACT) ? __expf(logit - m) : 0.0f;
      float se = wsum64(e);
      float swl = wsum64(e * logit);
      float lse = m + __logf(se);
      if (lane == 0) out[8704 + b] = lse - swl / se;                  // entropy
      int act = (int)out[b];                                          // action (written by init)
      if (lane == act) out[8448 + b] = logit - lse;                   // log_prob
    }
  } else {  // enc: es2[j] = dinv[j] * (hidden[0].msg_w[j] + msgb[j])
    int wg = (blk - 64) * 8 + wave;  // 0..1535
    for (int j = wg; j < NA; j += 1536) {
      const float* wp = &msgw[j * 512 + lane * 8];
      float4 w0 = *(const float4*)(wp);
      float4 w1 = *(const float4*)(wp + 4);
      float4 h0 = *(const float4*)&hidden[lane * 8];
      float4 h1 = *(const float4*)&hidden[lane * 8 + 4];
      float s = w0.x * h0.x + w0.y * h0.y + w0.z * h0.z + w0.w * h0.w +
                w1.x * h1.x + w1.y * h1.y + w1.z * h1.z + w1.w * h1.w;
      s = wsum64(s);
      if (lane == 0) es2[j] = dinv[j] * (s + msgb[j]);
    }
  }
  gridbar(bar, 2);

  //================ P3: GCN1 gather (4 rows per wave) ================
  {
    int wg = blk * 8 + wave;  // 0..2047
#pragma unroll
    for (int rr = 0; rr < 4; rr++) {
      int i = wg * 4 + rr;
      int ci = min(cnt[i], CSR_CAP);
      float di = dinv[i];
      float a0 = 0.0f, a1 = 0.0f;
      for (int e = lane; e < ci; e += 64) {
        int s = csr[i * CSR_CAP + e];
        a0 += xs2[s];
        a1 += es2[s];
      }
      // self-loop coeff is di^2: di*(sum_s xs2[s] + xs2[i]) = di*sum + di^2*x_i
      float f0 = (wsum64(a0) + xs2[i]) * di;
      float f1 = (wsum64(a1) + es2[i]) * di;
      if (lane < 16) {
        float gv = fmaxf(f0 * g1w[lane] + f1 * g1w[16 + lane] + g1b[lane], 0.0f);
        gbuf2[i * 16 + lane] = di * gv;
      }
    }
  }
  gridbar(bar, 3);

  //================ P4: GCN2 gather + wstats + MFMA scores + sum-exp ================
  {
    int rowbase = blk * 32;
    {  // gather 32 V rows: 8 waves x 4 rows; lanes = 4 edge-groups x 16 cols
      int eq = lane >> 4, c = lane & 15;
#pragma unroll
      for (int rr = 0; rr < 4; rr++) {
        int il = wave * 4 + rr;
        int i = rowbase + il;
        int ci = min(cnt[i], CSR_CAP);
        float di = dinv[i];
        float acc = (eq == 0) ? gbuf2[i * 16 + c] : 0.0f;  // self: di*(... + gbuf2[i]) = di^2*g_i
        for (int e = eq; e < ci; e += 4) {
          int s = csr[i * CSR_CAP + e];
          acc += gbuf2[s * 16 + c];
        }
        acc *= di;
        acc += __shfl_xor(acc, 16, 64);
        acc += __shfl_xor(acc, 32, 64);
        if (eq == 0) {
          sm.mg.vf[il * 16 + c] = acc;
          sm.mg.vbf[il * 16 + c] = f2bf(acc * LOG2E);  // pre-scale for exp2
        }
      }
    }
    __syncthreads();
    if (t < 272) {  // wstats reduce from per-block partials
      int bq = t / 17, k = t - bq * 17;
      float s = 0.0f;
      for (int b = bq; b < 256; b += 16) s += wpart[b * 17 + k];
      sm.mg.wp[bq][k] = s;
    }
    __syncthreads();
    if (t < 17) {
      float s = 0.0f;
#pragma unroll
      for (int q = 0; q < 16; q++) s += sm.mg.wp[q][t];
      sm.mg.wsf[t] = s;
    }
    __syncthreads();
    float myMean = 0.0f;
    if (t < 32) {
      float dot = 0.0f;
#pragma unroll
      for (int c = 0; c < 16; c++) dot += sm.mg.vf[t * 16 + c] * sm.mg.wsf[c];
      myMean = (dot + sm.mg.wsf[16]) * (1.0f / 8192.0f);
    }
    {  // scores via MFMA (log2e-scaled) + exp2; each wave owns a 1024-col slice
      int quad = lane >> 4, n = lane & 15;
      int k8 = quad * 8;
      short8 za = {0, 0, 0, 0, 0, 0, 0, 0};
      short8 a1 = za, a2 = za;
      if (quad < 2) {  // K padded 16->32
        a1 = *(const short8*)&sm.mg.vbf[n * 16 + k8];
        a2 = *(const short8*)&sm.mg.vbf[(16 + n) * 16 + k8];
      }
      float sacc[8];
#pragma unroll
      for (int q = 0; q < 8; q++) sacc[q] = 0.0f;
      int colb = wave * 1024 + n;
      for (int tp = 0; tp < 64; tp += 2) {
        int col1 = colb + tp * 16;
        int col2 = col1 + 16;
        short8 b1 = za, b2 = za;
        if (quad < 2) {
          b1 = *(const short8*)&w2t[col1 * 16 + k8];
          b2 = *(const short8*)&w2t[col2 * 16 + k8];
        }
        float bb1 = g2b[col1] * LOG2E, bb2 = g2b[col2] * LOG2E;
        float4v c1 = {bb1, bb1, bb1, bb1};
        float4v c2 = {bb2, bb2, bb2, bb2};
        float4v s11 = __builtin_amdgcn_mfma_f32_16x16x32_bf16(a1, b1, c1, 0, 0, 0);
        float4v s21 = __builtin_amdgcn_mfma_f32_16x16x32_bf16(a2, b1, c1, 0, 0, 0);
        float4v s12 = __builtin_amdgcn_mfma_f32_16x16x32_bf16(a1, b2, c2, 0, 0, 0);
        float4v s22 = __builtin_amdgcn_mfma_f32_16x16x32_bf16(a2, b2, c2, 0, 0, 0);
#pragma unroll
        for (int r = 0; r < 4; r++) {
          sacc[r]     += EXP2F(s11[r]) + EXP2F(s12[r]);
          sacc[4 + r] += EXP2F(s21[r]) + EXP2F(s22[r]);
        }
      }
#pragma unroll
      for (int q = 0; q < 8; q++) {
        int rl = (q >> 2) * 16 + quad * 4 + (q & 3);  // C/D row = quad*4+reg (+16 for A2)
        sm.mg.pl[rl * 128 + wave * 16 + n] = sacc[q];
      }
    }
    __syncthreads();
    if (t < 256) {
      int r = t >> 3, seg = t & 7;
      int base = r * 128 + seg * 16;
      float ll = 0.0f;
#pragma unroll
      for (int i = 0; i < 16; i++) ll += sm.mg.pl[base + i];
      sm.mg.sl[r * 8 + seg] = ll;
    }
    __syncthreads();
    if (t < 32) {
      float ll = 0.0f;
#pragma unroll
      for (int i = 0; i < 8; i++) ll += sm.mg.sl[t * 8 + i];
      out[256 + rowbase + t] = myMean - __logf(ll);  // ll = sum exp(s), exact
    }
  }
}

extern "C" void kernel_launch(void* const* d_in, const int* in_sizes, int n_in,
                              void* d_out, int out_size, void* d_ws, size_t ws_size,
                              hipStream_t stream) {
  const float* x     = (const float*)d_in[0];
  const float* x_msg = (const float*)d_in[1];
  const int*   edges = (const int*)d_in[2];
  const int*   action= (const int*)d_in[3];
  const float* c1w   = (const float*)d_in[4];
  const float* c1b   = (const float*)d_in[5];
  const float* c2w   = (const float*)d_in[6];
  const float* c2b   = (const float*)d_in[7];
  const float* fcw   = (const float*)d_in[8];
  const float* fcb   = (const float*)d_in[9];
  const float* muw   = (const float*)d_in[10];
  const float* mub   = (const float*)d_in[11];
  const float* msgw  = (const float*)d_in[12];
  const float* msgb  = (const float*)d_in[13];
  const float* g1w   = (const float*)d_in[14];
  const float* g1b   = (const float*)d_in[15];
  const float* g2w   = (const float*)d_in[16];
  const float* g2b   = (const float*)d_in[17];
  float* out = (float*)d_out;  // reference outputs are fp32

  float* ws     = (float*)d_ws;
  unsigned short* h1024bf = (unsigned short*)ws;            // 262144 bf16 = 131072 f
  unsigned short* fcwbf   = (unsigned short*)(ws + 131072); // 524288 bf16 = 262144 f
  float* hidden = ws + 393216;           // 131072
  float* es2    = ws + 524288;           // 8192
  float* dinv   = ws + 532480;           // 8192
  float* xs2    = ws + 540672;           // 8192
  float* gbuf2  = ws + 548864;           // 131072
  float* wpart  = ws + 679936;           // 4352
  unsigned short* w2t = (unsigned short*)(ws + 684288);     // 131072 bf16 = 65536 f
  int*   cnt    = (int*)(ws + 749824);   // 8192
  int*   csr    = (int*)(ws + 758016);   // 1048576
  int*   bar    = (int*)(ws + 1806592);  // 16

  k_init<<<33, 256, 0, stream>>>(action, cnt, bar, out);
  k_mega<<<NBLK, NTHR, 0, stream>>>(x, x_msg, edges, c1w, c1b, c2w, c2b, fcw, fcb,
                                    muw, mub, msgw, msgb, g1w, g1b, g2w, g2b,
                                    h1024bf, fcwbf, hidden, es2, dinv, xs2, gbuf2,
                                    wpart, w2t, cnt, csr, bar, out);
}

// Round 11
// 188.027 us; speedup vs baseline: 2.0527x; 1.1796x over previous
//
#include <hip/hip_runtime.h>
#include <hip/hip_bf16.h>

// Problem constants
#define NB 256
#define NACT 21
#define NA 8192
#define NE 262144
#define CSR_CAP 128
#define LOG2E 1.44269504f

#if __has_builtin(__builtin_amdgcn_exp2f)
#define EXP2F(x) __builtin_amdgcn_exp2f(x)
#else
#define EXP2F(x) exp2f(x)
#endif

typedef __attribute__((ext_vector_type(8))) short short8;
typedef __attribute__((ext_vector_type(4))) float float4v;

__device__ inline float wsum64(float v) {
#pragma unroll
  for (int m = 32; m > 0; m >>= 1) v += __shfl_xor(v, m, 64);
  return v;
}

__device__ inline unsigned short f2bf(float f) {
  union { __hip_bfloat16 h; unsigned short u; } cv;
  cv.h = __float2bfloat16(f);
  return cv.u;
}

// ---------------- k_init: zero cnt + action passthrough ----------------
__global__ void k_init(const int* action, int* cnt, float* out) {
  int i = blockIdx.x * 256 + threadIdx.x;  // 33*256
  if (i < NA) cnt[i] = 0;
  if (i < NB) out[i] = (float)action[i];
}

// ---------------- k_prep: CSR build + fcw->bf16 + W2 transpose/partials ----------------
__global__ __launch_bounds__(512, 4) void k_prep(
    const int* __restrict__ edges, const float* __restrict__ fcw,
    const float* __restrict__ g2w, const float* __restrict__ g2b,
    unsigned short* fcwbf, unsigned short* w2t, float* wpart, int* cnt, int* csr) {
  __shared__ float red[16][17];
  __shared__ float b2s[16];
  int t = threadIdx.x, blk = blockIdx.x;
  {  // CSR: 1 edge per thread (512*512 = NE)
    int e = blk * 512 + t;
    int s = edges[2 * e], d = edges[2 * e + 1];
    int slot = atomicAdd(&cnt[d], 1);
    if (slot < CSR_CAP) csr[d * CSR_CAP + slot] = s;
  }
  {  // fcw -> bf16: 2 floats per thread
    int base = (blk * 512 + t) * 2;
    float2 v = *(const float2*)&fcw[base];
    fcwbf[base + 0] = f2bf(v.x);
    fcwbf[base + 1] = f2bf(v.y);
  }
  {  // W2: block owns 16 cols; w2t[j][k] = W2[k][j] bf16; column partial sums
    if (t < 256) {
      int jj = t >> 4, k = t & 15;
      int j = blk * 16 + jj;
      float w = g2w[k * 8192 + j];
      w2t[j * 16 + k] = f2bf(w);
      red[jj][k] = w;
    }
    if (t < 16) b2s[t] = g2b[blk * 16 + t];
    __syncthreads();
    if (t < 16) {
      float s = 0.0f;
#pragma unroll
      for (int q = 0; q < 16; q++) s += red[q][t];
      wpart[blk * 17 + t] = s;
    } else if (t == 16) {
      float s = 0.0f;
#pragma unroll
      for (int q = 0; q < 16; q++) s += b2s[q];
      wpart[blk * 17 + 16] = s;
    }
  }
}

// ---------------- k_conv: fused conv1+conv2, one block per image ----------------
__global__ __launch_bounds__(512, 2) void k_conv(
    const float* __restrict__ x, const float* __restrict__ c1w, const float* __restrict__ c1b,
    const float* __restrict__ c2w, const float* __restrict__ c2b, unsigned short* h1024bf) {
  __shared__ float xs[845];
  __shared__ float w1s[1440];
  __shared__ float c1s[1152];
  __shared__ float w2s[64 * 73];
  int t = threadIdx.x, blk = blockIdx.x;
  for (int i = t; i < 845; i += 512) xs[i] = x[blk * 845 + i];
  for (int i = t; i < 1440; i += 512) w1s[i] = c1w[i];
  __syncthreads();
  for (int idx = t; idx < 1152; idx += 512) {
    int oc = idx / 36, p = idx - oc * 36;
    int oy = p / 6, ox = p - oy * 6;
    float acc = c1b[oc];
    const float* wp = &w1s[oc * 45];
#pragma unroll
    for (int ic = 0; ic < 5; ic++)
#pragma unroll
      for (int ky = 0; ky < 3; ky++)
#pragma unroll
        for (int kx = 0; kx < 3; kx++)
          acc += xs[ic * 169 + (oy * 2 + ky) * 13 + ox * 2 + kx] * wp[ic * 9 + ky * 3 + kx];
    c1s[idx] = fmaxf(acc, 0.0f);
  }
  int p = t & 15, oc2 = t >> 4;  // 2 output channels per thread
  int oy = p >> 2, ox = p & 3;
  float a0 = c2b[oc2 * 2 + 0], a1 = c2b[oc2 * 2 + 1];
  for (int icb = 0; icb < 32; icb += 8) {
    __syncthreads();
    for (int i = t; i < 4608; i += 512) {
      int oc = i / 72, r = i - oc * 72;
      w2s[oc * 73 + r] = c2w[oc * 288 + icb * 9 + r];
    }
    __syncthreads();
#pragma unroll
    for (int ic = 0; ic < 8; ic++) {
#pragma unroll
      for (int ky = 0; ky < 3; ky++) {
#pragma unroll
        for (int kx = 0; kx < 3; kx++) {
          float cvv = c1s[(icb + ic) * 36 + (oy + ky) * 6 + ox + kx];
          int wi = ic * 9 + ky * 3 + kx;
          a0 += cvv * w2s[(oc2 * 2 + 0) * 73 + wi];
          a1 += cvv * w2s[(oc2 * 2 + 1) * 73 + wi];
        }
      }
    }
  }
  unsigned short* hp = &h1024bf[blk * 1024];
  hp[(oc2 * 2 + 0) * 16 + p] = f2bf(fmaxf(a0, 0.0f));
  hp[(oc2 * 2 + 1) * 16 + p] = f2bf(fmaxf(a1, 0.0f));
}

// ---------------- k_fc: FC via bf16 MFMA (1 tile/block, K-split 4) + dinv/xs2 ----------------
__global__ __launch_bounds__(256, 4) void k_fc(
    const int* __restrict__ cnt, const float* __restrict__ x_msg,
    const unsigned short* __restrict__ h1024bf, const unsigned short* __restrict__ fcwbf,
    const float* __restrict__ fcb, float* hidden, float* dinv, float* xs2) {
  __shared__ float red[4][256];
  int t = threadIdx.x, blk = blockIdx.x;
  int wave = t >> 6, lane = t & 63;
  if (blk < 32) {
    int i = blk * 256 + t;
    float d = rsqrtf((float)cnt[i] + 1.0f);
    dinv[i] = d;
    xs2[i] = d * x_msg[i];
  }
  int tr = blk >> 5, tc = blk & 31;  // 16 row-tiles x 32 col-tiles
  int m = lane & 15, quad = lane >> 4;
  const unsigned short* ap = &h1024bf[(tr * 16 + m) * 1024 + wave * 256 + quad * 8];
  const unsigned short* bp = &fcwbf[(tc * 16 + m) * 1024 + wave * 256 + quad * 8];
  float4v acc = {0.0f, 0.0f, 0.0f, 0.0f};
#pragma unroll
  for (int i = 0; i < 8; i++) {
    short8 a = *(const short8*)(ap + i * 32);
    short8 b = *(const short8*)(bp + i * 32);
    acc = __builtin_amdgcn_mfma_f32_16x16x32_bf16(a, b, acc, 0, 0, 0);
  }
#pragma unroll
  for (int r = 0; r < 4; r++) red[wave][(quad * 4 + r) * 16 + m] = acc[r];
  __syncthreads();
  {  // reduce 4 K-slices + bias + relu
    float s = red[0][t] + red[1][t] + red[2][t] + red[3][t];
    int gr = tr * 16 + (t >> 4);
    int gc = tc * 16 + (t & 15);
    hidden[gr * 512 + gc] = fmaxf(s + fcb[gc], 0.0f);
  }
}

// ---------------- k_he: head (blocks 0..63) | enc (blocks 64..511) ----------------
__global__ __launch_bounds__(512, 2) void k_he(
    const float* __restrict__ hidden, const float* __restrict__ muw,
    const float* __restrict__ mub, const float* __restrict__ msgw,
    const float* __restrict__ msgb, const float* __restrict__ dinv,
    float* es2, float* out) {
  __shared__ float muT[10752];
  __shared__ float hrows[2048];
  int t = threadIdx.x, blk = blockIdx.x;
  int wave = t >> 6, lane = t & 63;
  if (blk < 64) {  // head: 4 batch rows per block
    int b0 = blk * 4;
    for (int i = t; i < 10752; i += 512) {
      int a = i >> 9, k = i & 511;
      muT[k * 21 + a] = muw[i];
    }
    for (int i = t; i < 2048; i += 512) hrows[i] = hidden[b0 * 512 + i];
    __syncthreads();
    if (wave < 4) {
      int b = b0 + wave;
      float logit = -1e30f;
      if (lane < NACT) {
        float acc = mub[lane];
        const float* hr = &hrows[wave * 512];
        for (int k = 0; k < 512; k++) acc += hr[k] * muT[k * 21 + lane];
        logit = acc;
      }
      float m = logit;
#pragma unroll
      for (int s = 32; s > 0; s >>= 1) m = fmaxf(m, __shfl_xor(m, s, 64));
      float e = (lane < NACT) ? __expf(logit - m) : 0.0f;
      float se = wsum64(e);
      float swl = wsum64(e * logit);
      float lse = m + __logf(se);
      if (lane == 0) out[8704 + b] = lse - swl / se;  // entropy
      int act = (int)out[b];                          // action (from k_init)
      if (lane == act) out[8448 + b] = logit - lse;   // log_prob
    }
  } else {  // enc: es2[j] = dinv[j] * (hidden[0].msg_w[j] + msgb[j])
    int wg = (blk - 64) * 8 + wave;  // 0..3583
    for (int j = wg; j < NA; j += 3584) {
      const float* wp = &msgw[j * 512 + lane * 8];
      float4 w0 = *(const float4*)(wp);
      float4 w1 = *(const float4*)(wp + 4);
      float4 h0 = *(const float4*)&hidden[lane * 8];
      float4 h1 = *(const float4*)&hidden[lane * 8 + 4];
      float s = w0.x * h0.x + w0.y * h0.y + w0.z * h0.z + w0.w * h0.w +
                w1.x * h1.x + w1.y * h1.y + w1.z * h1.z + w1.w * h1.w;
      s = wsum64(s);
      if (lane == 0) es2[j] = dinv[j] * (s + msgb[j]);
    }
  }
}

// ---------------- k_g1: GCN1 gather (2 rows per wave, 512 blocks) ----------------
__global__ __launch_bounds__(512, 4) void k_g1(
    const int* __restrict__ cnt, const int* __restrict__ csr,
    const float* __restrict__ dinv, const float* __restrict__ xs2,
    const float* __restrict__ es2, const float* __restrict__ g1w,
    const float* __restrict__ g1b, float* gbuf2) {
  int t = threadIdx.x, blk = blockIdx.x;
  int wave = t >> 6, lane = t & 63;
  int wg = blk * 8 + wave;  // 0..4095
#pragma unroll
  for (int rr = 0; rr < 2; rr++) {
    int i = wg * 2 + rr;
    int ci = min(cnt[i], CSR_CAP);
    float di = dinv[i];
    float a0 = 0.0f, a1 = 0.0f;
    for (int e = lane; e < ci; e += 64) {
      int s = csr[i * CSR_CAP + e];
      a0 += xs2[s];
      a1 += es2[s];
    }
    // self-loop coeff di^2: di*(sum_s dinv[s]x[s] + dinv[i]x[i])
    float f0 = (wsum64(a0) + xs2[i]) * di;
    float f1 = (wsum64(a1) + es2[i]) * di;
    if (lane < 16) {
      float gv = fmaxf(f0 * g1w[lane] + f1 * g1w[16 + lane] + g1b[lane], 0.0f);
      gbuf2[i * 16 + lane] = di * gv;
    }
  }
}

// ---------------- k_msg: GCN2 gather + wstats + MFMA scores + sum-exp ----------------
__global__ __launch_bounds__(512, 2) void k_msg(
    const int* __restrict__ cnt, const int* __restrict__ csr,
    const float* __restrict__ dinv, const float* __restrict__ gbuf2,
    const float* __restrict__ wpart, const unsigned short* __restrict__ w2t,
    const float* __restrict__ g2b, float* out) {
  __shared__ __align__(16) unsigned short vbf[512];
  __shared__ float vf[512];
  __shared__ float pl[4096];
  __shared__ float sl[256];
  __shared__ float wp[16][17];
  __shared__ float wsf[17];
  int t = threadIdx.x, blk = blockIdx.x;
  int wave = t >> 6, lane = t & 63;
  int rowbase = blk * 32;
  {  // gather 32 V rows: 8 waves x 4 rows; lanes = 4 edge-groups x 16 cols
    int eq = lane >> 4, c = lane & 15;
#pragma unroll
    for (int rr = 0; rr < 4; rr++) {
      int il = wave * 4 + rr;
      int i = rowbase + il;
      int ci = min(cnt[i], CSR_CAP);
      float di = dinv[i];
      float acc = (eq == 0) ? gbuf2[i * 16 + c] : 0.0f;  // self: di*(...+gbuf2[i]) = di^2*g_i
      for (int e = eq; e < ci; e += 4) {
        int s = csr[i * CSR_CAP + e];
        acc += gbuf2[s * 16 + c];
      }
      acc *= di;
      acc += __shfl_xor(acc, 16, 64);
      acc += __shfl_xor(acc, 32, 64);
      if (eq == 0) {
        vf[il * 16 + c] = acc;
        vbf[il * 16 + c] = f2bf(acc * LOG2E);  // pre-scale for exp2
      }
    }
  }
  __syncthreads();
  if (t < 272) {  // wstats reduce from 512 per-block partials
    int bq = t / 17, k = t - bq * 17;
    float s = 0.0f;
    for (int b = bq; b < 512; b += 16) s += wpart[b * 17 + k];
    wp[bq][k] = s;
  }
  __syncthreads();
  if (t < 17) {
    float s = 0.0f;
#pragma unroll
    for (int q = 0; q < 16; q++) s += wp[q][t];
    wsf[t] = s;
  }
  __syncthreads();
  float myMean = 0.0f;
  if (t < 32) {
    float dot = 0.0f;
#pragma unroll
    for (int c = 0; c < 16; c++) dot += vf[t * 16 + c] * wsf[c];
    myMean = (dot + wsf[16]) * (1.0f / 8192.0f);
  }
  {  // scores via MFMA (log2e-scaled) + exp2; each wave owns a 1024-col slice
    int quad = lane >> 4, n = lane & 15;
    int k8 = quad * 8;
    short8 za = {0, 0, 0, 0, 0, 0, 0, 0};
    short8 a1 = za, a2 = za;
    if (quad < 2) {  // K padded 16->32
      a1 = *(const short8*)&vbf[n * 16 + k8];
      a2 = *(const short8*)&vbf[(16 + n) * 16 + k8];
    }
    float sacc[8];
#pragma unroll
    for (int q = 0; q < 8; q++) sacc[q] = 0.0f;
    int colb = wave * 1024 + n;
    for (int tp = 0; tp < 64; tp += 2) {
      int col1 = colb + tp * 16;
      int col2 = col1 + 16;
      short8 b1 = za, b2 = za;
      if (quad < 2) {
        b1 = *(const short8*)&w2t[col1 * 16 + k8];
        b2 = *(const short8*)&w2t[col2 * 16 + k8];
      }
      float bb1 = g2b[col1] * LOG2E, bb2 = g2b[col2] * LOG2E;
      float4v c1 = {bb1, bb1, bb1, bb1};
      float4v c2 = {bb2, bb2, bb2, bb2};
      float4v s11 = __builtin_amdgcn_mfma_f32_16x16x32_bf16(a1, b1, c1, 0, 0, 0);
      float4v s21 = __builtin_amdgcn_mfma_f32_16x16x32_bf16(a2, b1, c1, 0, 0, 0);
      float4v s12 = __builtin_amdgcn_mfma_f32_16x16x32_bf16(a1, b2, c2, 0, 0, 0);
      float4v s22 = __builtin_amdgcn_mfma_f32_16x16x32_bf16(a2, b2, c2, 0, 0, 0);
#pragma unroll
      for (int r = 0; r < 4; r++) {
        sacc[r]     += EXP2F(s11[r]) + EXP2F(s12[r]);
        sacc[4 + r] += EXP2F(s21[r]) + EXP2F(s22[r]);
      }
    }
#pragma unroll
    for (int q = 0; q < 8; q++) {
      int rl = (q >> 2) * 16 + quad * 4 + (q & 3);  // C/D row = quad*4+reg (+16 for A2)
      pl[rl * 128 + wave * 16 + n] = sacc[q];
    }
  }
  __syncthreads();
  if (t < 256) {
    int r = t >> 3, seg = t & 7;
    int base = r * 128 + seg * 16;
    float ll = 0.0f;
#pragma unroll
    for (int i = 0; i < 16; i++) ll += pl[base + i];
    sl[r * 8 + seg] = ll;
  }
  __syncthreads();
  if (t < 32) {
    float ll = 0.0f;
#pragma unroll
    for (int i = 0; i < 8; i++) ll += sl[t * 8 + i];
    out[256 + rowbase + t] = myMean - __logf(ll);  // ll = sum exp(s)
  }
}

extern "C" void kernel_launch(void* const* d_in, const int* in_sizes, int n_in,
                              void* d_out, int out_size, void* d_ws, size_t ws_size,
                              hipStream_t stream) {
  const float* x     = (const float*)d_in[0];
  const float* x_msg = (const float*)d_in[1];
  const int*   edges = (const int*)d_in[2];
  const int*   action= (const int*)d_in[3];
  const float* c1w   = (const float*)d_in[4];
  const float* c1b   = (const float*)d_in[5];
  const float* c2w   = (const float*)d_in[6];
  const float* c2b   = (const float*)d_in[7];
  const float* fcw   = (const float*)d_in[8];
  const float* fcb   = (const float*)d_in[9];
  const float* muw   = (const float*)d_in[10];
  const float* mub   = (const float*)d_in[11];
  const float* msgw  = (const float*)d_in[12];
  const float* msgb  = (const float*)d_in[13];
  const float* g1w   = (const float*)d_in[14];
  const float* g1b   = (const float*)d_in[15];
  const float* g2w   = (const float*)d_in[16];
  const float* g2b   = (const float*)d_in[17];
  float* out = (float*)d_out;  // reference outputs are fp32

  float* ws     = (float*)d_ws;
  unsigned short* h1024bf = (unsigned short*)ws;            // 262144 bf16 = 131072 f
  unsigned short* fcwbf   = (unsigned short*)(ws + 131072); // 524288 bf16 = 262144 f
  float* hidden = ws + 393216;           // 131072
  float* es2    = ws + 524288;           // 8192
  float* dinv   = ws + 532480;           // 8192
  float* xs2    = ws + 540672;           // 8192
  float* gbuf2  = ws + 548864;           // 131072
  float* wpart  = ws + 679936;           // 8704
  unsigned short* w2t = (unsigned short*)(ws + 688640);     // 131072 bf16 = 65536 f
  int*   cnt    = (int*)(ws + 754176);   // 8192
  int*   csr    = (int*)(ws + 762368);   // 1048576  -> total ~7.2 MB

  k_init<<<33, 256, 0, stream>>>(action, cnt, out);
  k_prep<<<512, 512, 0, stream>>>(edges, fcw, g2w, g2b, fcwbf, w2t, wpart, cnt, csr);
  k_conv<<<256, 512, 0, stream>>>(x, c1w, c1b, c2w, c2b, h1024bf);
  k_fc  <<<512, 256, 0, stream>>>(cnt, x_msg, h1024bf, fcwbf, fcb, hidden, dinv, xs2);
  k_he  <<<512, 512, 0, stream>>>(hidden, muw, mub, msgw, msgb, dinv, es2, out);
  k_g1  <<<512, 512, 0, stream>>>(cnt, csr, dinv, xs2, es2, g1w, g1b, gbuf2);
  k_msg <<<256, 512, 0, stream>>>(cnt, csr, dinv, gbuf2, wpart, w2t, g2b, out);
}